// Round 2
// baseline (242.618 us; speedup 1.0000x reference)
//
#include <hip/hip_runtime.h>

#define DCH 512     // channels
#define RPB 16      // rows per block

__global__ __launch_bounds__(128) void ppeg_dwconv_kernel(
    const float* __restrict__ x,
    const float* __restrict__ w3, const float* __restrict__ b3,
    const float* __restrict__ w5, const float* __restrict__ b5,
    const float* __restrict__ w7, const float* __restrict__ b7,
    const int* __restrict__ lengths,
    float* __restrict__ out, int n_rows, int n_bags)
{
    __shared__ int soff[32];   // prefix offsets, n_bags+1 entries
    if (threadIdx.x == 0) {
        int acc = 0;
        for (int i = 0; i < n_bags; ++i) { soff[i] = acc; acc += lengths[i]; }
        soff[n_bags] = acc;
    }
    __syncthreads();

    const int tid = threadIdx.x;
    const int c0  = tid * 4;           // this thread's 4 channels

    // Combine the three depthwise kernels into one 7-tap kernel + bias per channel.
    // dt = -3..3 maps to W[0..6]; dt=0 tap gets +1.0 for the residual.
    float W[7][4], bias[4];
    #pragma unroll
    for (int q = 0; q < 4; ++q) {
        const int d = c0 + q;
        const float a0 = w7[d*7+0], a1 = w7[d*7+1], a2 = w7[d*7+2], a3 = w7[d*7+3],
                    a4 = w7[d*7+4], a5 = w7[d*7+5], a6 = w7[d*7+6];
        const float f0 = w5[d*5+0], f1 = w5[d*5+1], f2 = w5[d*5+2], f3 = w5[d*5+3], f4 = w5[d*5+4];
        const float e0 = w3[d*3+0], e1 = w3[d*3+1], e2 = w3[d*3+2];
        W[0][q] = a0;
        W[1][q] = a1 + f0;
        W[2][q] = a2 + f1 + e0;
        W[3][q] = a3 + f2 + e1 + 1.0f;
        W[4][q] = a4 + f3 + e2;
        W[5][q] = a5 + f4;
        W[6][q] = a6;
        bias[q] = b3[d] + b5[d] + b7[d];
    }

    const int r0 = blockIdx.x * RPB;
    if (r0 >= n_rows) return;

    // Starting bag for r0 (wave-uniform; bags are large so this loop is short).
    int b = 0;
    while (b + 1 < n_bags && soff[b + 1] <= r0) ++b;

    // Register sliding window: win[j] holds row (r - 3 + j) of this thread's 4 channels.
    float4 win[7];
    #pragma unroll
    for (int j = 0; j < 6; ++j) {
        const int rr = r0 - 3 + j;
        win[j] = (rr >= 0 && rr < n_rows)
                   ? *(const float4*)(x + (size_t)rr * DCH + c0)
                   : make_float4(0.f, 0.f, 0.f, 0.f);
    }

    for (int i = 0; i < RPB; ++i) {
        const int r = r0 + i;
        if (r >= n_rows) break;

        const int rr = r + 3;
        win[6] = (rr < n_rows)
                   ? *(const float4*)(x + (size_t)rr * DCH + c0)
                   : make_float4(0.f, 0.f, 0.f, 0.f);

        while (b + 1 < n_bags && soff[b + 1] <= r) ++b;
        const int t = r - soff[b] - 1;     // body position; -1 => cls row

        float4 o;
        if (t < 0) {
            o = win[3];                    // cls row: pass-through
        } else {
            const int Lb1 = soff[b + 1] - soff[b] - 1;   // body length
            float acc0 = bias[0], acc1 = bias[1], acc2 = bias[2], acc3 = bias[3];
            #pragma unroll
            for (int dt = -3; dt <= 3; ++dt) {
                const bool valid = (t + dt >= 0) && (t + dt < Lb1);
                const float m = valid ? 1.0f : 0.0f;
                const float4 v = win[dt + 3];
                acc0 += m * W[dt + 3][0] * v.x;
                acc1 += m * W[dt + 3][1] * v.y;
                acc2 += m * W[dt + 3][2] * v.z;
                acc3 += m * W[dt + 3][3] * v.w;
            }
            o = make_float4(acc0, acc1, acc2, acc3);
        }

        *(float4*)(out + (size_t)r * DCH + c0) = o;

        #pragma unroll
        for (int j = 0; j < 6; ++j) win[j] = win[j + 1];
    }
}

extern "C" void kernel_launch(void* const* d_in, const int* in_sizes, int n_in,
                              void* d_out, int out_size, void* d_ws, size_t ws_size,
                              hipStream_t stream) {
    const float* x       = (const float*)d_in[0];
    const float* w3      = (const float*)d_in[1];
    const float* b3      = (const float*)d_in[2];
    const float* w5      = (const float*)d_in[3];
    const float* b5      = (const float*)d_in[4];
    const float* w7      = (const float*)d_in[5];
    const float* b7      = (const float*)d_in[6];
    const int*   lengths = (const int*)d_in[7];

    const int n_bags = in_sizes[7];
    const int n_rows = in_sizes[0] / DCH;
    float* out = (float*)d_out;

    const int nblocks = (n_rows + RPB - 1) / RPB;
    ppeg_dwconv_kernel<<<nblocks, 128, 0, stream>>>(
        x, w3, b3, w5, b5, w7, b7, lengths, out, n_rows, n_bags);
}